// Round 3
// baseline (803.583 us; speedup 1.0000x reference)
//
#include <hip/hip_runtime.h>
#include <hip/hip_bf16.h>
#include <stdint.h>

// ---------------------------------------------------------------------------
// GNNEncoder: 3 x (GCNConv -> BatchNorm1d(train) -> ELU)
// N=50000, E=1.6M, dims 128->128->128->64
//
// R3:
//  - CSR build: block-local LDS histogram (packed u16) -> column prefix in
//    place -> two-level scan -> atomic-free scatter.  No global atomics.
//  - AGG: column-sliced (16 cols/slice), slice-major h/y so each slice
//    (1.6MB) stays resident in one XCD's L2 via blockIdx round-robin.
//  - GEMM/colsum/out adapted to slice-major layout.
// ---------------------------------------------------------------------------

#define NB 128   // histogram / scatter blocks (edge chunks)

static __device__ __forceinline__ float bflo(uint32_t u) {
    union { uint32_t u; float f; } x; x.u = u << 16; return x.f;
}
static __device__ __forceinline__ float bfhi(uint32_t u) {
    union { uint32_t u; float f; } x; x.u = u & 0xffff0000u; return x.f;
}
static __device__ __forceinline__ uint16_t f2bf(float f) {
    union { float f; uint32_t u; } x; x.f = f;
    uint32_t r = x.u + 0x7fffu + ((x.u >> 16) & 1u);   // RNE
    return (uint16_t)(r >> 16);
}
static __device__ __forceinline__ float eluf(float v) {
    return v > 0.f ? v : expm1f(v);
}

// ------------------------------------------------ phase A: LDS histogram
// hist packs 2 nodes per u32 (u16 counters). rank16[e] = block-local rank.
__global__ __launch_bounds__(1024) void hist_rank_kernel(
    const int* __restrict__ dst, uint32_t* __restrict__ blockHist,
    uint16_t* __restrict__ rank16, int E, int EPB, int nwords) {
    __shared__ uint32_t hist[25088];          // up to n=50176 nodes
    int b = blockIdx.x, t = threadIdx.x;
    for (int i = t; i < nwords; i += 1024) hist[i] = 0;
    __syncthreads();
    int e0 = b * EPB, e1 = min(E, e0 + EPB);
    for (int e = e0 + t; e < e1; e += 1024) {
        int d = dst[e];
        uint32_t sh = (uint32_t)(d & 1) * 16u;
        uint32_t old = atomicAdd(&hist[d >> 1], 1u << sh);
        rank16[e] = (uint16_t)((old >> sh) & 0xffffu);
    }
    __syncthreads();
    uint32_t* out = blockHist + (size_t)b * nwords;
    for (int i = t; i < nwords; i += 1024) out[i] = hist[i];
}

// --------------------------------- phase C: column prefix over blocks
// In-place: blockHist[b][word] := packed prefix (sum over b' < b).
// Also emits packed degree, dis, and per-chunk (512-node) sums.
__global__ __launch_bounds__(256) void colprefix_kernel(
    uint32_t* __restrict__ blockHist, uint32_t* __restrict__ deg16,
    float* __restrict__ dis, int* __restrict__ chunkSum, int n, int nwords) {
    int t = threadIdx.x;
    int wid = blockIdx.x * 256 + t;
    uint32_t run0 = 0, run1 = 0;
    if (wid < nwords) {
        size_t idx = wid;
        for (int b = 0; b < NB; ++b, idx += nwords) {
            uint32_t w = blockHist[idx];
            blockHist[idx] = run0 | (run1 << 16);
            run0 += w & 0xffffu;
            run1 += w >> 16;
        }
        deg16[wid] = run0 | (run1 << 16);
        int n0 = wid * 2, n1 = n0 + 1;
        if (n0 < n) dis[n0] = rsqrtf(1.0f + (float)run0);
        if (n1 < n) dis[n1] = rsqrtf(1.0f + (float)run1);
    }
    __shared__ int red[256];
    red[t] = (wid < nwords) ? (int)(run0 + run1) : 0;
    __syncthreads();
    for (int s = 128; s > 0; s >>= 1) {
        if (t < s) red[t] += red[t + s];
        __syncthreads();
    }
    if (t == 0) chunkSum[blockIdx.x] = red[0];
}

// ------------------------------------------- scan chunk sums (nc <= 256)
__global__ __launch_bounds__(256) void scan2_kernel(
    const int* __restrict__ chunkSum, int* __restrict__ chunkBase,
    int* __restrict__ row_start, int n, int nc) {
    __shared__ int wtot[4];
    int t = threadIdx.x, lane = t & 63, w = t >> 6;
    int v = (t < nc) ? chunkSum[t] : 0;
    int x = v;
    #pragma unroll
    for (int off = 1; off < 64; off <<= 1) {
        int m = __shfl_up(x, off);
        if (lane >= off) x += m;
    }
    if (lane == 63) wtot[w] = x;
    __syncthreads();
    int woff = 0, tot = 0;
    #pragma unroll
    for (int j = 0; j < 4; ++j) {
        int wv = wtot[j];
        tot += wv;
        if (j < w) woff += wv;
    }
    if (t < nc) chunkBase[t] = woff + x - v;   // exclusive
    if (t == 0) row_start[n] = tot;
}

// --------------------------------------- row_start: per-chunk 512 scan
__global__ __launch_bounds__(512) void rowstart_kernel(
    const uint32_t* __restrict__ deg16, const int* __restrict__ chunkBase,
    int* __restrict__ row_start, int n) {
    __shared__ int wtot[8];
    int t = threadIdx.x, lane = t & 63, w = t >> 6;
    int node = blockIdx.x * 512 + t;
    int v = 0;
    if (node < n) {
        uint32_t d = deg16[node >> 1];
        v = (int)((d >> ((node & 1) * 16)) & 0xffffu);
    }
    int x = v;
    #pragma unroll
    for (int off = 1; off < 64; off <<= 1) {
        int m = __shfl_up(x, off);
        if (lane >= off) x += m;
    }
    if (lane == 63) wtot[w] = x;
    __syncthreads();
    int woff = 0;
    for (int j = 0; j < w; ++j) woff += wtot[j];
    if (node < n) row_start[node] = chunkBase[blockIdx.x] + woff + x - v;
}

// ----------------------------------------------------- atomic-free scatter
__global__ __launch_bounds__(1024) void scatter_kernel(
    const int* __restrict__ src, const int* __restrict__ dst,
    const uint16_t* __restrict__ rank16, const uint32_t* __restrict__ blockHist,
    const int* __restrict__ row_start, int* __restrict__ csr_src,
    int E, int EPB, int nwords) {
    int b = blockIdx.x, t = threadIdx.x;
    const uint32_t* base = blockHist + (size_t)b * nwords;
    int e0 = b * EPB, e1 = min(E, e0 + EPB);
    for (int e = e0 + t; e < e1; e += 1024) {
        int d = dst[e];
        uint32_t pre = (base[d >> 1] >> ((d & 1) * 16)) & 0xffffu;
        int pos = row_start[d] + (int)pre + (int)rank16[e];
        csr_src[pos] = src[e];
    }
}

// ------------------------------------------------------------------- GEMM
// h (bf16, slice-major [F/16][n][16]) = act(in)[n][128] @ W[128][F]
// in: row-major [n][128] (layer 0) or slice-major [8][n][16] (layers 1,2).
template <int F, bool BN, bool SLICED_IN>
__global__ __launch_bounds__(512) void gemm_kernel(
    const float* __restrict__ in, const float* __restrict__ W,
    const float* __restrict__ sc, const float* __restrict__ sh,
    uint16_t* __restrict__ h, int n) {
    constexpr int K = 128;
    constexpr int BM = 128;
    __shared__ float xs[K][BM + 4];
    __shared__ float ws[K][F];
    int t = threadIdx.x;
    int row0 = blockIdx.x * BM;

    for (int i = t * 4; i < K * F; i += 512 * 4) {
        *(float4*)((float*)ws + i) = *(const float4*)(W + i);
    }
    for (int idx = t; idx < BM * K / 4; idx += 512) {
        int r = idx >> 5;
        int k4 = (idx & 31) << 2;            // global col index of float4
        int gr = row0 + r;
        float4 v = make_float4(0.f, 0.f, 0.f, 0.f);
        if (gr < n) {
            const float* p;
            if (SLICED_IN)
                p = in + (size_t)(k4 >> 4) * ((size_t)n * 16) + (size_t)gr * 16 + (k4 & 15);
            else
                p = in + (size_t)gr * K + k4;
            v = *(const float4*)p;
        }
        if (BN) {
            float4 s4 = *(const float4*)(sc + k4);
            float4 h4 = *(const float4*)(sh + k4);
            v.x = eluf(v.x * s4.x + h4.x);
            v.y = eluf(v.y * s4.y + h4.y);
            v.z = eluf(v.z * s4.z + h4.z);
            v.w = eluf(v.w * s4.w + h4.w);
        }
        xs[k4 + 0][r] = v.x;
        xs[k4 + 1][r] = v.y;
        xs[k4 + 2][r] = v.z;
        xs[k4 + 3][r] = v.w;
    }
    __syncthreads();

    constexpr int CW = F / 16;               // 8 (F=128) or 4 (F=64)
    int tx = t & 15;
    int ty = t >> 4;
    float acc[4][CW];
    #pragma unroll
    for (int r = 0; r < 4; ++r)
        #pragma unroll
        for (int c = 0; c < CW; ++c) acc[r][c] = 0.f;

    for (int k = 0; k < K; ++k) {
        float4 xv = *(const float4*)&xs[k][ty * 4];
        float wv[CW];
        *(float4*)wv = *(const float4*)&ws[k][tx * CW];
        if (CW == 8) *(float4*)(wv + 4) = *(const float4*)&ws[k][tx * CW + 4];
        const float* xp = &xv.x;
        #pragma unroll
        for (int r = 0; r < 4; ++r)
            #pragma unroll
            for (int c = 0; c < CW; ++c)
                acc[r][c] = fmaf(xp[r], wv[c], acc[r][c]);
    }

    int col0 = tx * CW;
    int slice = col0 >> 4, off = col0 & 15;
    #pragma unroll
    for (int r = 0; r < 4; ++r) {
        int row = row0 + ty * 4 + r;
        if (row < n) {
            uint16_t* dstp = h + ((size_t)slice * n + row) * 16 + off;
            uint32_t p[CW / 2];
            #pragma unroll
            for (int c = 0; c < CW; c += 2)
                p[c / 2] = (uint32_t)f2bf(acc[r][c]) | ((uint32_t)f2bf(acc[r][c + 1]) << 16);
            if (CW == 8) *(uint4*)dstp = make_uint4(p[0], p[1], p[2], p[3]);
            else         *(uint2*)dstp = make_uint2(p[0], p[1]);
        }
    }
}

// -------------------------------------------------------------------- AGG
// Column-sliced: block handles slice = bid & (S-1)  (XCD round-robin pins
// each slice's h data in one XCD L2), node group = bid >> log2(S).
// Wave: 8 edge-groups x 8 col-pairs; xor-shuffle reduce over edge-groups.
template <int S>
__global__ __launch_bounds__(256) void agg_kernel(
    const uint32_t* __restrict__ hp,     // h as u32: (slice*n+node)*8 + cp
    const int* __restrict__ row_start, const int* __restrict__ csr_src,
    const float* __restrict__ dis, const float* __restrict__ bias,
    float* __restrict__ y, int n) {      // y: (slice*n+node)*16 + c
    constexpr int SH = (S == 8) ? 3 : 2;
    int bid = blockIdx.x;
    int slice = bid & (S - 1);
    int grp = bid >> SH;
    int wv = threadIdx.x >> 6, lane = threadIdx.x & 63;
    int node = grp * 4 + wv;
    if (node >= n) return;
    int s = row_start[node], e = row_start[node + 1];
    float dd = dis[node];
    int eg = lane >> 3, cp = lane & 7;
    const uint32_t* hs = hp + (size_t)slice * n * 8;
    float a0 = 0.f, a1 = 0.f;
    for (int i = s + eg; i < e; i += 8) {
        int sr = csr_src[i];
        float c = dis[sr] * dd;
        uint32_t u = hs[(size_t)sr * 8 + cp];
        a0 = fmaf(c, bflo(u), a0);
        a1 = fmaf(c, bfhi(u), a1);
    }
    a0 += __shfl_xor(a0, 8);  a1 += __shfl_xor(a1, 8);
    a0 += __shfl_xor(a0, 16); a1 += __shfl_xor(a1, 16);
    a0 += __shfl_xor(a0, 32); a1 += __shfl_xor(a1, 32);
    if (lane < 8) {
        uint32_t u = hs[(size_t)node * 8 + cp];
        float c2 = dd * dd;
        int col = slice * 16 + cp * 2;
        a0 = fmaf(c2, bflo(u), a0) + bias[col];
        a1 = fmaf(c2, bfhi(u), a1) + bias[col + 1];
        *(float2*)(y + ((size_t)slice * n + node) * 16 + cp * 2) = make_float2(a0, a1);
    }
}

// ------------------------------------------------------------ BN statistics
// y slice-major; grid = (rowChunks, S).
__global__ __launch_bounds__(256) void colsum_kernel(
    const float* __restrict__ y, int n,
    float* __restrict__ sums, float* __restrict__ sumsq) {
    int slice = blockIdx.y;
    const float* ys = y + (size_t)slice * n * 16;
    int t = threadIdx.x, cg = t & 3, rt = t >> 2;      // 64 row-threads
    float4 s = make_float4(0.f, 0.f, 0.f, 0.f);
    float4 q = make_float4(0.f, 0.f, 0.f, 0.f);
    for (int row = blockIdx.x * 64 + rt; row < n; row += gridDim.x * 64) {
        float4 v = *(const float4*)(ys + (size_t)row * 16 + cg * 4);
        s.x += v.x; s.y += v.y; s.z += v.z; s.w += v.w;
        q.x += v.x * v.x; q.y += v.y * v.y; q.z += v.z * v.z; q.w += v.w * v.w;
    }
    __shared__ float4 rs[64][4], rq[64][4];
    rs[rt][cg] = s; rq[rt][cg] = q;
    __syncthreads();
    for (int st = 32; st > 0; st >>= 1) {
        if (rt < st) {
            float4 o = rs[rt + st][cg], p = rq[rt + st][cg];
            rs[rt][cg].x += o.x; rs[rt][cg].y += o.y;
            rs[rt][cg].z += o.z; rs[rt][cg].w += o.w;
            rq[rt][cg].x += p.x; rq[rt][cg].y += p.y;
            rq[rt][cg].z += p.z; rq[rt][cg].w += p.w;
        }
        __syncthreads();
    }
    if (rt == 0) {
        float4 fs = rs[0][cg], fq = rq[0][cg];
        int col = slice * 16 + cg * 4;
        atomicAdd(&sums[col + 0], fs.x); atomicAdd(&sums[col + 1], fs.y);
        atomicAdd(&sums[col + 2], fs.z); atomicAdd(&sums[col + 3], fs.w);
        atomicAdd(&sumsq[col + 0], fq.x); atomicAdd(&sumsq[col + 1], fq.y);
        atomicAdd(&sumsq[col + 2], fq.z); atomicAdd(&sumsq[col + 3], fq.w);
    }
}

template <int F>
__global__ void finalize_kernel(const float* __restrict__ sums,
                                const float* __restrict__ sumsq,
                                const float* __restrict__ g, const float* __restrict__ be,
                                float* __restrict__ sc, float* __restrict__ sh, float n) {
    int c = threadIdx.x;
    if (c < F) {
        float m = sums[c] / n;
        float v = sumsq[c] / n - m * m;
        float r = rsqrtf(v + 1e-5f);
        float scale = r * g[c];
        sc[c] = scale;
        sh[c] = be[c] - m * scale;
    }
}

// ----------------------------------------------------------- final BN+ELU
// y slice-major [4][n][16] -> out row-major [n][64]
__global__ __launch_bounds__(256) void out_kernel(
    const float* __restrict__ y, const float* __restrict__ sc,
    const float* __restrict__ sh, float* __restrict__ out, int n) {
    int idx = blockIdx.x * 256 + threadIdx.x;
    if (idx >= n * 16) return;
    int node = idx >> 4, q = idx & 15;
    int slice = q >> 2, c4 = (q & 3) * 4;
    int col = slice * 16 + c4;
    float4 v = *(const float4*)(y + ((size_t)slice * n + node) * 16 + c4);
    float4 s4 = *(const float4*)(sc + col);
    float4 h4 = *(const float4*)(sh + col);
    v.x = eluf(v.x * s4.x + h4.x);
    v.y = eluf(v.y * s4.y + h4.y);
    v.z = eluf(v.z * s4.z + h4.z);
    v.w = eluf(v.w * s4.w + h4.w);
    *(float4*)(out + (size_t)node * 64 + q * 4) = v;
}

// ---------------------------------------------------------------------------
extern "C" void kernel_launch(void* const* d_in, const int* in_sizes, int n_in,
                              void* d_out, int out_size, void* d_ws, size_t ws_size,
                              hipStream_t stream) {
    const float* x   = (const float*)d_in[0];
    const int*   edge = (const int*)d_in[1];
    const float* W0 = (const float*)d_in[2];
    const float* b0 = (const float*)d_in[3];
    const float* g0 = (const float*)d_in[4];
    const float* be0 = (const float*)d_in[5];
    const float* W1 = (const float*)d_in[6];
    const float* b1 = (const float*)d_in[7];
    const float* g1 = (const float*)d_in[8];
    const float* be1 = (const float*)d_in[9];
    const float* W2 = (const float*)d_in[10];
    const float* b2 = (const float*)d_in[11];
    const float* g2 = (const float*)d_in[12];
    const float* be2 = (const float*)d_in[13];

    const int n = in_sizes[0] / 128;     // 50000
    const int E = in_sizes[1] / 2;       // 1600000
    const int* esrc = edge;
    const int* edst = edge + E;

    const int nwords  = (n + 1) / 2;               // packed u16 words
    const int nchunks = (n + 511) / 512;           // 512-node chunks
    const int EPB     = (E + NB - 1) / NB;

    char* w = (char*)d_ws;
    auto carve = [&](size_t bytes) -> void* {
        void* p = (void*)w;
        w += (bytes + 255) & ~(size_t)255;
        return p;
    };
    float*    y         = (float*)carve((size_t)n * 128 * 4);     // slice-major
    uint16_t* h         = (uint16_t*)carve((size_t)n * 128 * 2);  // slice-major
    int*      csr_src   = (int*)carve((size_t)E * 4);
    uint16_t* rank16    = (uint16_t*)carve((size_t)E * 2);
    uint32_t* blockHist = (uint32_t*)carve((size_t)NB * nwords * 4);
    uint32_t* deg16     = (uint32_t*)carve((size_t)nwords * 4);
    int*      row_start = (int*)carve((size_t)(n + 1) * 4);
    float*    dis       = (float*)carve((size_t)n * 4);
    int*      chunkSum  = (int*)carve((size_t)nchunks * 4 + 256);
    int*      chunkBase = (int*)carve((size_t)nchunks * 4 + 256);
    float*    sums      = (float*)carve(128 * 4);
    float*    sumsq     = (float*)carve(128 * 4);
    float*    sc        = (float*)carve(128 * 4);
    float*    sh        = (float*)carve(128 * 4);

    // ---- CSR build (atomic-free)
    hist_rank_kernel<<<NB, 1024, 0, stream>>>(edst, blockHist, rank16, E, EPB, nwords);
    colprefix_kernel<<<(nwords + 255) / 256, 256, 0, stream>>>(
        blockHist, deg16, dis, chunkSum, n, nwords);
    scan2_kernel<<<1, 256, 0, stream>>>(chunkSum, chunkBase, row_start, n, nchunks);
    rowstart_kernel<<<nchunks, 512, 0, stream>>>(deg16, chunkBase, row_start, n);
    scatter_kernel<<<NB, 1024, 0, stream>>>(esrc, edst, rank16, blockHist,
                                            row_start, csr_src, E, EPB, nwords);

    const uint32_t* hp = (const uint32_t*)h;
    int gGemm = (n + 127) / 128;
    int gGrp  = (n + 3) / 4;

    // ---- layer 0
    gemm_kernel<128, false, false><<<gGemm, 512, 0, stream>>>(x, W0, nullptr, nullptr, h, n);
    agg_kernel<8><<<gGrp * 8, 256, 0, stream>>>(hp, row_start, csr_src, dis, b0, y, n);
    hipMemsetAsync(sums, 0, 128 * 4, stream);
    hipMemsetAsync(sumsq, 0, 128 * 4, stream);
    colsum_kernel<<<dim3(64, 8), 256, 0, stream>>>(y, n, sums, sumsq);
    finalize_kernel<128><<<1, 128, 0, stream>>>(sums, sumsq, g0, be0, sc, sh, (float)n);

    // ---- layer 1
    gemm_kernel<128, true, true><<<gGemm, 512, 0, stream>>>(y, W1, sc, sh, h, n);
    agg_kernel<8><<<gGrp * 8, 256, 0, stream>>>(hp, row_start, csr_src, dis, b1, y, n);
    hipMemsetAsync(sums, 0, 128 * 4, stream);
    hipMemsetAsync(sumsq, 0, 128 * 4, stream);
    colsum_kernel<<<dim3(64, 8), 256, 0, stream>>>(y, n, sums, sumsq);
    finalize_kernel<128><<<1, 128, 0, stream>>>(sums, sumsq, g1, be1, sc, sh, (float)n);

    // ---- layer 2 (F=64 -> 4 slices)
    gemm_kernel<64, true, true><<<gGemm, 512, 0, stream>>>(y, W2, sc, sh, h, n);
    agg_kernel<4><<<gGrp * 4, 256, 0, stream>>>(hp, row_start, csr_src, dis, b2, y, n);
    hipMemsetAsync(sums, 0, 64 * 4, stream);
    hipMemsetAsync(sumsq, 0, 64 * 4, stream);
    colsum_kernel<<<dim3(64, 4), 256, 0, stream>>>(y, n, sums, sumsq);
    finalize_kernel<64><<<1, 64, 0, stream>>>(sums, sumsq, g2, be2, sc, sh, (float)n);

    // ---- final BN2 + ELU -> out (row-major f32)
    out_kernel<<<(n * 16 + 255) / 256, 256, 0, stream>>>(y, sc, sh, (float*)d_out, n);
}

// Round 4
// 576.733 us; speedup vs baseline: 1.3933x; 1.3933x over previous
//
#include <hip/hip_runtime.h>
#include <hip/hip_bf16.h>
#include <stdint.h>

// ---------------------------------------------------------------------------
// GNNEncoder: 3 x (GCNConv -> BatchNorm1d(train) -> ELU)
// N=50000, E=1.6M, dims 128->128->128->64
//
// R4:
//  - agg: wave-per-node row-major gather (R2 structure) with unroll-16
//    load-then-FMA to put 16 gathers in flight per wave (latency-bound fix).
//  - CSR build: R3's atomic-free histogram path (kept).
//  - GEMM/colsum/out: R2 row-major versions (kept).
// ---------------------------------------------------------------------------

#define NB 128   // histogram / scatter blocks (edge chunks)

static __device__ __forceinline__ float bflo(uint32_t u) {
    union { uint32_t u; float f; } x; x.u = u << 16; return x.f;
}
static __device__ __forceinline__ float bfhi(uint32_t u) {
    union { uint32_t u; float f; } x; x.u = u & 0xffff0000u; return x.f;
}
static __device__ __forceinline__ uint16_t f2bf(float f) {
    union { float f; uint32_t u; } x; x.f = f;
    uint32_t r = x.u + 0x7fffu + ((x.u >> 16) & 1u);   // RNE
    return (uint16_t)(r >> 16);
}
static __device__ __forceinline__ float eluf(float v) {
    return v > 0.f ? v : expm1f(v);
}

// ------------------------------------------------ phase A: LDS histogram
__global__ __launch_bounds__(1024) void hist_rank_kernel(
    const int* __restrict__ dst, uint32_t* __restrict__ blockHist,
    uint16_t* __restrict__ rank16, int E, int EPB, int nwords) {
    __shared__ uint32_t hist[25088];          // up to n=50176 nodes
    int b = blockIdx.x, t = threadIdx.x;
    for (int i = t; i < nwords; i += 1024) hist[i] = 0;
    __syncthreads();
    int e0 = b * EPB, e1 = min(E, e0 + EPB);
    for (int e = e0 + t; e < e1; e += 1024) {
        int d = dst[e];
        uint32_t sh = (uint32_t)(d & 1) * 16u;
        uint32_t old = atomicAdd(&hist[d >> 1], 1u << sh);
        rank16[e] = (uint16_t)((old >> sh) & 0xffffu);
    }
    __syncthreads();
    uint32_t* out = blockHist + (size_t)b * nwords;
    for (int i = t; i < nwords; i += 1024) out[i] = hist[i];
}

// --------------------------------- phase C: column prefix over blocks
__global__ __launch_bounds__(256) void colprefix_kernel(
    uint32_t* __restrict__ blockHist, uint32_t* __restrict__ deg16,
    float* __restrict__ dis, int* __restrict__ chunkSum, int n, int nwords) {
    int t = threadIdx.x;
    int wid = blockIdx.x * 256 + t;
    uint32_t run0 = 0, run1 = 0;
    if (wid < nwords) {
        size_t idx = wid;
        for (int b = 0; b < NB; ++b, idx += nwords) {
            uint32_t w = blockHist[idx];
            blockHist[idx] = run0 | (run1 << 16);
            run0 += w & 0xffffu;
            run1 += w >> 16;
        }
        deg16[wid] = run0 | (run1 << 16);
        int n0 = wid * 2, n1 = n0 + 1;
        if (n0 < n) dis[n0] = rsqrtf(1.0f + (float)run0);
        if (n1 < n) dis[n1] = rsqrtf(1.0f + (float)run1);
    }
    __shared__ int red[256];
    red[t] = (wid < nwords) ? (int)(run0 + run1) : 0;
    __syncthreads();
    for (int s = 128; s > 0; s >>= 1) {
        if (t < s) red[t] += red[t + s];
        __syncthreads();
    }
    if (t == 0) chunkSum[blockIdx.x] = red[0];
}

// ------------------------------------------- scan chunk sums (nc <= 256)
__global__ __launch_bounds__(256) void scan2_kernel(
    const int* __restrict__ chunkSum, int* __restrict__ chunkBase,
    int* __restrict__ row_start, int n, int nc) {
    __shared__ int wtot[4];
    int t = threadIdx.x, lane = t & 63, w = t >> 6;
    int v = (t < nc) ? chunkSum[t] : 0;
    int x = v;
    #pragma unroll
    for (int off = 1; off < 64; off <<= 1) {
        int m = __shfl_up(x, off);
        if (lane >= off) x += m;
    }
    if (lane == 63) wtot[w] = x;
    __syncthreads();
    int woff = 0, tot = 0;
    #pragma unroll
    for (int j = 0; j < 4; ++j) {
        int wv = wtot[j];
        tot += wv;
        if (j < w) woff += wv;
    }
    if (t < nc) chunkBase[t] = woff + x - v;   // exclusive
    if (t == 0) row_start[n] = tot;
}

// --------------------------------------- row_start: per-chunk 512 scan
__global__ __launch_bounds__(512) void rowstart_kernel(
    const uint32_t* __restrict__ deg16, const int* __restrict__ chunkBase,
    int* __restrict__ row_start, int n) {
    __shared__ int wtot[8];
    int t = threadIdx.x, lane = t & 63, w = t >> 6;
    int node = blockIdx.x * 512 + t;
    int v = 0;
    if (node < n) {
        uint32_t d = deg16[node >> 1];
        v = (int)((d >> ((node & 1) * 16)) & 0xffffu);
    }
    int x = v;
    #pragma unroll
    for (int off = 1; off < 64; off <<= 1) {
        int m = __shfl_up(x, off);
        if (lane >= off) x += m;
    }
    if (lane == 63) wtot[w] = x;
    __syncthreads();
    int woff = 0;
    for (int j = 0; j < w; ++j) woff += wtot[j];
    if (node < n) row_start[node] = chunkBase[blockIdx.x] + woff + x - v;
}

// ----------------------------------------------------- atomic-free scatter
__global__ __launch_bounds__(1024) void scatter_kernel(
    const int* __restrict__ src, const int* __restrict__ dst,
    const uint16_t* __restrict__ rank16, const uint32_t* __restrict__ blockHist,
    const int* __restrict__ row_start, int* __restrict__ csr_src,
    int E, int EPB, int nwords) {
    int b = blockIdx.x, t = threadIdx.x;
    const uint32_t* base = blockHist + (size_t)b * nwords;
    int e0 = b * EPB, e1 = min(E, e0 + EPB);
    for (int e = e0 + t; e < e1; e += 1024) {
        int d = dst[e];
        uint32_t pre = (base[d >> 1] >> ((d & 1) * 16)) & 0xffffu;
        int pos = row_start[d] + (int)pre + (int)rank16[e];
        csr_src[pos] = src[e];
    }
}

// ------------------------------------------------------------------- GEMM
// h[n][F] (bf16) = act(in)[n][128] @ W[128][F];  act = BN+ELU (fused) or id.
template <int F, bool BN>
__global__ __launch_bounds__(512) void gemm_kernel(
    const float* __restrict__ in, const float* __restrict__ W,
    const float* __restrict__ sc, const float* __restrict__ sh,
    uint16_t* __restrict__ h, int n) {
    constexpr int K = 128;
    constexpr int BM = 128;
    __shared__ float xs[K][BM + 4];   // transposed: xs[k][r]
    __shared__ float ws[K][F];
    int t = threadIdx.x;
    int row0 = blockIdx.x * BM;

    for (int i = t * 4; i < K * F; i += 512 * 4) {
        *(float4*)((float*)ws + i) = *(const float4*)(W + i);
    }
    for (int idx = t; idx < BM * K / 4; idx += 512) {
        int r = idx >> 5;
        int k = (idx & 31) << 2;
        int gr = row0 + r;
        float4 v = make_float4(0.f, 0.f, 0.f, 0.f);
        if (gr < n) v = *(const float4*)(in + (size_t)gr * K + k);
        if (BN) {
            float4 s4 = *(const float4*)(sc + k);
            float4 h4 = *(const float4*)(sh + k);
            v.x = eluf(v.x * s4.x + h4.x);
            v.y = eluf(v.y * s4.y + h4.y);
            v.z = eluf(v.z * s4.z + h4.z);
            v.w = eluf(v.w * s4.w + h4.w);
        }
        xs[k + 0][r] = v.x;
        xs[k + 1][r] = v.y;
        xs[k + 2][r] = v.z;
        xs[k + 3][r] = v.w;
    }
    __syncthreads();

    constexpr int CW = F / 16;
    int tx = t & 15;
    int ty = t >> 4;
    float acc[4][CW];
    #pragma unroll
    for (int r = 0; r < 4; ++r)
        #pragma unroll
        for (int c = 0; c < CW; ++c) acc[r][c] = 0.f;

    for (int k = 0; k < K; ++k) {
        float4 xv = *(const float4*)&xs[k][ty * 4];
        float wv[CW];
        *(float4*)wv = *(const float4*)&ws[k][tx * CW];
        if (CW == 8) *(float4*)(wv + 4) = *(const float4*)&ws[k][tx * CW + 4];
        const float* xp = &xv.x;
        #pragma unroll
        for (int r = 0; r < 4; ++r)
            #pragma unroll
            for (int c = 0; c < CW; ++c)
                acc[r][c] = fmaf(xp[r], wv[c], acc[r][c]);
    }

    #pragma unroll
    for (int r = 0; r < 4; ++r) {
        int row = row0 + ty * 4 + r;
        if (row < n) {
            uint32_t p[CW / 2];
            #pragma unroll
            for (int c = 0; c < CW; c += 2)
                p[c / 2] = (uint32_t)f2bf(acc[r][c]) | ((uint32_t)f2bf(acc[r][c + 1]) << 16);
            if (CW == 8) {
                uint4 val = make_uint4(p[0], p[1], p[2], p[3]);
                *(uint4*)(h + (size_t)row * F + tx * CW) = val;
            } else {
                uint2 val = make_uint2(p[0], p[1]);
                *(uint2*)(h + (size_t)row * F + tx * CW) = val;
            }
        }
    }
}

// -------------------------------------------------------------------- AGG
// y[i] = sum_{e in CSR(i)} dis[src]*dis[i] * h[src] + dis_i^2 * h[i] + b
// wave-per-node; unroll-16 load-then-FMA: 16 gathers in flight per wave.
template <int F>
__global__ __launch_bounds__(256) void agg_kernel(
    const uint16_t* __restrict__ h,
    const int* __restrict__ row_start, const int* __restrict__ csr_src,
    const float* __restrict__ dis,
    const float* __restrict__ bias, float* __restrict__ y, int n) {
    int wid = (int)((blockIdx.x * 256 + threadIdx.x) >> 6);
    int lane = threadIdx.x & 63;
    if (wid >= n) return;
    int s = row_start[wid], e = row_start[wid + 1];
    float dd = dis[wid];

    if (F == 128) {
        const uint32_t* hp = (const uint32_t*)h;
        float a0 = 0.f, a1 = 0.f;
        int i = s;
        for (; i + 16 <= e; i += 16) {
            int sid[16];
            #pragma unroll
            for (int j = 0; j < 16; ++j) sid[j] = csr_src[i + j];
            uint32_t u[16];
            #pragma unroll
            for (int j = 0; j < 16; ++j) u[j] = hp[(size_t)sid[j] * 64 + lane];
            float c[16];
            #pragma unroll
            for (int j = 0; j < 16; ++j) c[j] = dis[sid[j]] * dd;
            #pragma unroll
            for (int j = 0; j < 16; ++j) {
                a0 = fmaf(c[j], bflo(u[j]), a0);
                a1 = fmaf(c[j], bfhi(u[j]), a1);
            }
        }
        for (; i + 4 <= e; i += 4) {
            int sid[4];
            #pragma unroll
            for (int j = 0; j < 4; ++j) sid[j] = csr_src[i + j];
            uint32_t u[4];
            #pragma unroll
            for (int j = 0; j < 4; ++j) u[j] = hp[(size_t)sid[j] * 64 + lane];
            #pragma unroll
            for (int j = 0; j < 4; ++j) {
                float c = dis[sid[j]] * dd;
                a0 = fmaf(c, bflo(u[j]), a0);
                a1 = fmaf(c, bfhi(u[j]), a1);
            }
        }
        for (; i < e; ++i) {
            int s0 = csr_src[i];
            float c0 = dis[s0] * dd;
            uint32_t u0 = hp[(size_t)s0 * 64 + lane];
            a0 = fmaf(c0, bflo(u0), a0);
            a1 = fmaf(c0, bfhi(u0), a1);
        }
        float c2 = dd * dd;
        uint32_t u = hp[(size_t)wid * 64 + lane];
        a0 = fmaf(c2, bflo(u), a0) + bias[2 * lane];
        a1 = fmaf(c2, bfhi(u), a1) + bias[2 * lane + 1];
        *(float2*)(y + (size_t)wid * 128 + 2 * lane) = make_float2(a0, a1);
    } else {
        float a0 = 0.f;
        int i = s;
        for (; i + 16 <= e; i += 16) {
            int sid[16];
            #pragma unroll
            for (int j = 0; j < 16; ++j) sid[j] = csr_src[i + j];
            uint32_t u[16];
            #pragma unroll
            for (int j = 0; j < 16; ++j) u[j] = (uint32_t)h[(size_t)sid[j] * 64 + lane];
            float c[16];
            #pragma unroll
            for (int j = 0; j < 16; ++j) c[j] = dis[sid[j]] * dd;
            #pragma unroll
            for (int j = 0; j < 16; ++j) a0 = fmaf(c[j], bflo(u[j]), a0);
        }
        for (; i + 4 <= e; i += 4) {
            int sid[4];
            #pragma unroll
            for (int j = 0; j < 4; ++j) sid[j] = csr_src[i + j];
            uint32_t u[4];
            #pragma unroll
            for (int j = 0; j < 4; ++j) u[j] = (uint32_t)h[(size_t)sid[j] * 64 + lane];
            #pragma unroll
            for (int j = 0; j < 4; ++j) {
                float c = dis[sid[j]] * dd;
                a0 = fmaf(c, bflo(u[j]), a0);
            }
        }
        for (; i < e; ++i) {
            int s0 = csr_src[i];
            float c0 = dis[s0] * dd;
            a0 = fmaf(c0, bflo((uint32_t)h[(size_t)s0 * 64 + lane]), a0);
        }
        float c2 = dd * dd;
        a0 = fmaf(c2, bflo((uint32_t)h[(size_t)wid * 64 + lane]), a0) + bias[lane];
        y[(size_t)wid * 64 + lane] = a0;
    }
}

// ------------------------------------------------------------ BN statistics
template <int F>
__global__ __launch_bounds__(256) void colsum_kernel(
    const float* __restrict__ y, int n,
    float* __restrict__ sums, float* __restrict__ sumsq) {
    constexpr int CG = F / 4;
    constexpr int RP = 256 / CG;
    int t = threadIdx.x;
    int cg = t % CG, rt = t / CG;
    float4 s = make_float4(0.f, 0.f, 0.f, 0.f);
    float4 q = make_float4(0.f, 0.f, 0.f, 0.f);
    for (int row = blockIdx.x * RP + rt; row < n; row += gridDim.x * RP) {
        float4 v = *(const float4*)(y + (size_t)row * F + cg * 4);
        s.x += v.x; s.y += v.y; s.z += v.z; s.w += v.w;
        q.x += v.x * v.x; q.y += v.y * v.y; q.z += v.z * v.z; q.w += v.w * v.w;
    }
    __shared__ float4 rs[RP][CG], rq[RP][CG];
    rs[rt][cg] = s; rq[rt][cg] = q;
    __syncthreads();
    if (rt == 0) {
        #pragma unroll 4
        for (int j = 1; j < RP; ++j) {
            float4 o = rs[j][cg], p = rq[j][cg];
            s.x += o.x; s.y += o.y; s.z += o.z; s.w += o.w;
            q.x += p.x; q.y += p.y; q.z += p.z; q.w += p.w;
        }
        atomicAdd(&sums[cg * 4 + 0], s.x); atomicAdd(&sums[cg * 4 + 1], s.y);
        atomicAdd(&sums[cg * 4 + 2], s.z); atomicAdd(&sums[cg * 4 + 3], s.w);
        atomicAdd(&sumsq[cg * 4 + 0], q.x); atomicAdd(&sumsq[cg * 4 + 1], q.y);
        atomicAdd(&sumsq[cg * 4 + 2], q.z); atomicAdd(&sumsq[cg * 4 + 3], q.w);
    }
}

template <int F>
__global__ void finalize_kernel(const float* __restrict__ sums,
                                const float* __restrict__ sumsq,
                                const float* __restrict__ g, const float* __restrict__ be,
                                float* __restrict__ sc, float* __restrict__ sh, float n) {
    int c = threadIdx.x;
    if (c < F) {
        float m = sums[c] / n;
        float v = sumsq[c] / n - m * m;           // biased variance
        float r = rsqrtf(v + 1e-5f);
        float scale = r * g[c];
        sc[c] = scale;
        sh[c] = be[c] - m * scale;
    }
}

// ----------------------------------------------------------- final BN+ELU
__global__ __launch_bounds__(256) void out_kernel(
    const float* __restrict__ y, const float* __restrict__ sc,
    const float* __restrict__ sh, float* __restrict__ out, int total4) {
    int idx = blockIdx.x * 256 + threadIdx.x;
    if (idx >= total4) return;
    int cg = (idx & 15) * 4;
    float4 v = *(const float4*)(y + (size_t)idx * 4);
    float4 s4 = *(const float4*)(sc + cg);
    float4 h4 = *(const float4*)(sh + cg);
    v.x = eluf(v.x * s4.x + h4.x);
    v.y = eluf(v.y * s4.y + h4.y);
    v.z = eluf(v.z * s4.z + h4.z);
    v.w = eluf(v.w * s4.w + h4.w);
    *(float4*)(out + (size_t)idx * 4) = v;
}

// ---------------------------------------------------------------------------
extern "C" void kernel_launch(void* const* d_in, const int* in_sizes, int n_in,
                              void* d_out, int out_size, void* d_ws, size_t ws_size,
                              hipStream_t stream) {
    const float* x   = (const float*)d_in[0];
    const int*   edge = (const int*)d_in[1];
    const float* W0 = (const float*)d_in[2];
    const float* b0 = (const float*)d_in[3];
    const float* g0 = (const float*)d_in[4];
    const float* be0 = (const float*)d_in[5];
    const float* W1 = (const float*)d_in[6];
    const float* b1 = (const float*)d_in[7];
    const float* g1 = (const float*)d_in[8];
    const float* be1 = (const float*)d_in[9];
    const float* W2 = (const float*)d_in[10];
    const float* b2 = (const float*)d_in[11];
    const float* g2 = (const float*)d_in[12];
    const float* be2 = (const float*)d_in[13];

    const int n = in_sizes[0] / 128;     // 50000
    const int E = in_sizes[1] / 2;       // 1600000
    const int* esrc = edge;
    const int* edst = edge + E;

    const int nwords  = (n + 1) / 2;
    const int nchunks = (n + 511) / 512;
    const int EPB     = (E + NB - 1) / NB;

    char* w = (char*)d_ws;
    auto carve = [&](size_t bytes) -> void* {
        void* p = (void*)w;
        w += (bytes + 255) & ~(size_t)255;
        return p;
    };
    float*    y         = (float*)carve((size_t)n * 128 * 4);
    uint16_t* h         = (uint16_t*)carve((size_t)n * 128 * 2);
    int*      csr_src   = (int*)carve((size_t)E * 4);
    uint16_t* rank16    = (uint16_t*)carve((size_t)E * 2);
    uint32_t* blockHist = (uint32_t*)carve((size_t)NB * nwords * 4);
    uint32_t* deg16     = (uint32_t*)carve((size_t)nwords * 4);
    int*      row_start = (int*)carve((size_t)(n + 1) * 4);
    float*    dis       = (float*)carve((size_t)n * 4);
    int*      chunkSum  = (int*)carve((size_t)nchunks * 4 + 256);
    int*      chunkBase = (int*)carve((size_t)nchunks * 4 + 256);
    float*    sums      = (float*)carve(128 * 4);
    float*    sumsq     = (float*)carve(128 * 4);
    float*    sc        = (float*)carve(128 * 4);
    float*    sh        = (float*)carve(128 * 4);

    // ---- CSR build (atomic-free)
    hist_rank_kernel<<<NB, 1024, 0, stream>>>(edst, blockHist, rank16, E, EPB, nwords);
    colprefix_kernel<<<(nwords + 255) / 256, 256, 0, stream>>>(
        blockHist, deg16, dis, chunkSum, n, nwords);
    scan2_kernel<<<1, 256, 0, stream>>>(chunkSum, chunkBase, row_start, n, nchunks);
    rowstart_kernel<<<nchunks, 512, 0, stream>>>(deg16, chunkBase, row_start, n);
    scatter_kernel<<<NB, 1024, 0, stream>>>(esrc, edst, rank16, blockHist,
                                            row_start, csr_src, E, EPB, nwords);

    int gGemm = (n + 127) / 128;
    int gAgg  = (n + 3) / 4;

    // ---- layer 0 (in = x, no BN on input)
    gemm_kernel<128, false><<<gGemm, 512, 0, stream>>>(x, W0, nullptr, nullptr, h, n);
    agg_kernel<128><<<gAgg, 256, 0, stream>>>(h, row_start, csr_src, dis, b0, y, n);
    hipMemsetAsync(sums, 0, 128 * 4, stream);
    hipMemsetAsync(sumsq, 0, 128 * 4, stream);
    colsum_kernel<128><<<256, 256, 0, stream>>>(y, n, sums, sumsq);
    finalize_kernel<128><<<1, 128, 0, stream>>>(sums, sumsq, g0, be0, sc, sh, (float)n);

    // ---- layer 1
    gemm_kernel<128, true><<<gGemm, 512, 0, stream>>>(y, W1, sc, sh, h, n);
    agg_kernel<128><<<gAgg, 256, 0, stream>>>(h, row_start, csr_src, dis, b1, y, n);
    hipMemsetAsync(sums, 0, 128 * 4, stream);
    hipMemsetAsync(sumsq, 0, 128 * 4, stream);
    colsum_kernel<128><<<256, 256, 0, stream>>>(y, n, sums, sumsq);
    finalize_kernel<128><<<1, 128, 0, stream>>>(sums, sumsq, g1, be1, sc, sh, (float)n);

    // ---- layer 2 (F=64)
    gemm_kernel<64, true><<<gGemm, 512, 0, stream>>>(y, W2, sc, sh, h, n);
    agg_kernel<64><<<gAgg, 256, 0, stream>>>(h, row_start, csr_src, dis, b2, y, n);
    hipMemsetAsync(sums, 0, 64 * 4, stream);
    hipMemsetAsync(sumsq, 0, 64 * 4, stream);
    colsum_kernel<64><<<256, 256, 0, stream>>>(y, n, sums, sumsq);
    finalize_kernel<64><<<1, 64, 0, stream>>>(sums, sumsq, g2, be2, sc, sh, (float)n);

    // ---- final BN2 + ELU -> out
    int total4 = n * 16;
    out_kernel<<<(total4 + 255) / 256, 256, 0, stream>>>(y, sc, sh, (float*)d_out, total4);
}

// Round 5
// 540.453 us; speedup vs baseline: 1.4869x; 1.0671x over previous
//
#include <hip/hip_runtime.h>
#include <hip/hip_bf16.h>
#include <stdint.h>

// ---------------------------------------------------------------------------
// GNNEncoder: 3 x (GCNConv -> BatchNorm1d(train) -> ELU)
// N=50000, E=1.6M, dims 128->128->128->64
//
// R5: CSR build = two-level counting sort with LOCALIZED writes.
//   P1 coarse hist (dst>>8 buckets) -> P2 base scan -> P3 partition into
//   bucket regions (packed 4B records, contiguous runs) -> P4 per-bucket
//   fine placement (LDS hist+scan, writes confined to bucket's region).
//   No global atomics; write amplification ~1.3x instead of ~9x.
// agg (unroll-16 wave-per-node), gemm, colsum, finalize, out: unchanged (R4).
// ---------------------------------------------------------------------------

#define NCH 256   // edge chunks (partition blocks)

static __device__ __forceinline__ float bflo(uint32_t u) {
    union { uint32_t u; float f; } x; x.u = u << 16; return x.f;
}
static __device__ __forceinline__ float bfhi(uint32_t u) {
    union { uint32_t u; float f; } x; x.u = u & 0xffff0000u; return x.f;
}
static __device__ __forceinline__ uint16_t f2bf(float f) {
    union { float f; uint32_t u; } x; x.f = f;
    uint32_t r = x.u + 0x7fffu + ((x.u >> 16) & 1u);   // RNE
    return (uint16_t)(r >> 16);
}
static __device__ __forceinline__ float eluf(float v) {
    return v > 0.f ? v : expm1f(v);
}

// --------------------------------------------- P1: coarse histogram
// bucket = dst >> 8 (256-node ranges), NBUK <= 256 (n <= 65536).
__global__ __launch_bounds__(1024) void hist_coarse_kernel(
    const int* __restrict__ dst, uint32_t* __restrict__ coarse,
    int E, int EPC, int NBUK) {
    __shared__ uint32_t cnt[256];
    int b = blockIdx.x, t = threadIdx.x;
    if (t < 256) cnt[t] = 0;
    __syncthreads();
    int e0 = b * EPC, e1 = min(E, e0 + EPC);
    for (int e = e0 + t; e < e1; e += 1024) atomicAdd(&cnt[dst[e] >> 8], 1u);
    __syncthreads();
    if (t < NBUK) coarse[(size_t)t * NCH + b] = cnt[t];
}

// --------------------------------------------- P2: base scan (1 block)
// coarse[buk][ch] := exclusive prefix over chunks (within bucket);
// bucketEdgeBase[buk] := exclusive scan of bucket totals; row_start[n]=E.
__global__ __launch_bounds__(1024) void basescan_kernel(
    uint32_t* __restrict__ coarse, int* __restrict__ beb,
    int* __restrict__ row_start, int NBUK, int E, int n) {
    __shared__ int btot[256];
    __shared__ int wt[4];
    int t = threadIdx.x;
    int sum = 0;
    if (t < NBUK) {
        uint32_t* rowp = coarse + (size_t)t * NCH;
        uint32_t run = 0;
        for (int ch = 0; ch < NCH; ++ch) {
            uint32_t v = rowp[ch];
            rowp[ch] = run;
            run += v;
        }
        sum = (int)run;
    }
    if (t < 256) btot[t] = (t < NBUK) ? sum : 0;
    __syncthreads();
    int x = 0, v = 0;
    if (t < 256) {
        int lane = t & 63, w = t >> 6;
        v = btot[t];
        x = v;
        #pragma unroll
        for (int off = 1; off < 64; off <<= 1) {
            int m = __shfl_up(x, off);
            if (lane >= off) x += m;
        }
        if (lane == 63) wt[w] = x;
    }
    __syncthreads();
    if (t < 256) {
        int w = t >> 6, woff = 0;
        for (int j = 0; j < w; ++j) woff += wt[j];
        int excl = woff + x - v;
        if (t < NBUK) beb[t] = excl;
    }
    if (t == 0) {
        beb[NBUK] = E;
        row_start[n] = E;
    }
}

// --------------------------------------------- P3: partition into buckets
// rec = (dst&255)<<16 | src  (requires n <= 65536)
__global__ __launch_bounds__(1024) void partition_kernel(
    const int* __restrict__ src, const int* __restrict__ dst,
    const uint32_t* __restrict__ coarse, const int* __restrict__ beb,
    uint32_t* __restrict__ rec, int E, int EPC, int NBUK) {
    __shared__ int cur[256];
    int b = blockIdx.x, t = threadIdx.x;
    if (t < NBUK) cur[t] = (int)coarse[(size_t)t * NCH + b] + beb[t];
    __syncthreads();
    int e0 = b * EPC, e1 = min(E, e0 + EPC);
    for (int e = e0 + t; e < e1; e += 1024) {
        int d = dst[e];
        int pos = atomicAdd(&cur[d >> 8], 1);
        rec[pos] = (uint32_t)src[e] | ((uint32_t)(d & 255) << 16);
    }
}

// --------------------------------------------- P4: fine placement per bucket
__global__ __launch_bounds__(1024) void fine_kernel(
    const uint32_t* __restrict__ rec, const int* __restrict__ beb,
    int* __restrict__ row_start, float* __restrict__ dis,
    int* __restrict__ csr_src, int n) {
    __shared__ int cnt[256];
    __shared__ int wt[4];
    int b = blockIdx.x, t = threadIdx.x;
    int e0 = beb[b], e1 = beb[b + 1];
    if (t < 256) cnt[t] = 0;
    __syncthreads();
    for (int i = e0 + t; i < e1; i += 1024)
        atomicAdd(&cnt[(rec[i] >> 16) & 255], 1);
    __syncthreads();
    int x = 0, deg = 0;
    if (t < 256) {
        int lane = t & 63, w = t >> 6;
        deg = cnt[t];
        x = deg;
        #pragma unroll
        for (int off = 1; off < 64; off <<= 1) {
            int m = __shfl_up(x, off);
            if (lane >= off) x += m;
        }
        if (lane == 63) wt[w] = x;
    }
    __syncthreads();
    int excl = 0;
    if (t < 256) {
        int w = t >> 6, woff = 0;
        for (int j = 0; j < w; ++j) woff += wt[j];
        excl = woff + x - deg;
        int node = (b << 8) + t;
        if (node < n) {
            row_start[node] = e0 + excl;
            dis[node] = rsqrtf(1.0f + (float)deg);
        }
    }
    __syncthreads();
    if (t < 256) cnt[t] = e0 + excl;
    __syncthreads();
    for (int i = e0 + t; i < e1; i += 1024) {
        uint32_t r = rec[i];
        int pos = atomicAdd(&cnt[(r >> 16) & 255], 1);
        csr_src[pos] = (int)(r & 0xffffu);
    }
}

// ------------------------------------------------------------------- GEMM
// h[n][F] (bf16) = act(in)[n][128] @ W[128][F];  act = BN+ELU (fused) or id.
template <int F, bool BN>
__global__ __launch_bounds__(512) void gemm_kernel(
    const float* __restrict__ in, const float* __restrict__ W,
    const float* __restrict__ sc, const float* __restrict__ sh,
    uint16_t* __restrict__ h, int n) {
    constexpr int K = 128;
    constexpr int BM = 128;
    __shared__ float xs[K][BM + 4];   // transposed: xs[k][r]
    __shared__ float ws[K][F];
    int t = threadIdx.x;
    int row0 = blockIdx.x * BM;

    for (int i = t * 4; i < K * F; i += 512 * 4) {
        *(float4*)((float*)ws + i) = *(const float4*)(W + i);
    }
    for (int idx = t; idx < BM * K / 4; idx += 512) {
        int r = idx >> 5;
        int k = (idx & 31) << 2;
        int gr = row0 + r;
        float4 v = make_float4(0.f, 0.f, 0.f, 0.f);
        if (gr < n) v = *(const float4*)(in + (size_t)gr * K + k);
        if (BN) {
            float4 s4 = *(const float4*)(sc + k);
            float4 h4 = *(const float4*)(sh + k);
            v.x = eluf(v.x * s4.x + h4.x);
            v.y = eluf(v.y * s4.y + h4.y);
            v.z = eluf(v.z * s4.z + h4.z);
            v.w = eluf(v.w * s4.w + h4.w);
        }
        xs[k + 0][r] = v.x;
        xs[k + 1][r] = v.y;
        xs[k + 2][r] = v.z;
        xs[k + 3][r] = v.w;
    }
    __syncthreads();

    constexpr int CW = F / 16;
    int tx = t & 15;
    int ty = t >> 4;
    float acc[4][CW];
    #pragma unroll
    for (int r = 0; r < 4; ++r)
        #pragma unroll
        for (int c = 0; c < CW; ++c) acc[r][c] = 0.f;

    for (int k = 0; k < K; ++k) {
        float4 xv = *(const float4*)&xs[k][ty * 4];
        float wv[CW];
        *(float4*)wv = *(const float4*)&ws[k][tx * CW];
        if (CW == 8) *(float4*)(wv + 4) = *(const float4*)&ws[k][tx * CW + 4];
        const float* xp = &xv.x;
        #pragma unroll
        for (int r = 0; r < 4; ++r)
            #pragma unroll
            for (int c = 0; c < CW; ++c)
                acc[r][c] = fmaf(xp[r], wv[c], acc[r][c]);
    }

    #pragma unroll
    for (int r = 0; r < 4; ++r) {
        int row = row0 + ty * 4 + r;
        if (row < n) {
            uint32_t p[CW / 2];
            #pragma unroll
            for (int c = 0; c < CW; c += 2)
                p[c / 2] = (uint32_t)f2bf(acc[r][c]) | ((uint32_t)f2bf(acc[r][c + 1]) << 16);
            if (CW == 8) {
                uint4 val = make_uint4(p[0], p[1], p[2], p[3]);
                *(uint4*)(h + (size_t)row * F + tx * CW) = val;
            } else {
                uint2 val = make_uint2(p[0], p[1]);
                *(uint2*)(h + (size_t)row * F + tx * CW) = val;
            }
        }
    }
}

// -------------------------------------------------------------------- AGG
// wave-per-node; unroll-16 load-then-FMA: 16 gathers in flight per wave.
template <int F>
__global__ __launch_bounds__(256) void agg_kernel(
    const uint16_t* __restrict__ h,
    const int* __restrict__ row_start, const int* __restrict__ csr_src,
    const float* __restrict__ dis,
    const float* __restrict__ bias, float* __restrict__ y, int n) {
    int wid = (int)((blockIdx.x * 256 + threadIdx.x) >> 6);
    int lane = threadIdx.x & 63;
    if (wid >= n) return;
    int s = row_start[wid], e = row_start[wid + 1];
    float dd = dis[wid];

    if (F == 128) {
        const uint32_t* hp = (const uint32_t*)h;
        float a0 = 0.f, a1 = 0.f;
        int i = s;
        for (; i + 16 <= e; i += 16) {
            int sid[16];
            #pragma unroll
            for (int j = 0; j < 16; ++j) sid[j] = csr_src[i + j];
            uint32_t u[16];
            #pragma unroll
            for (int j = 0; j < 16; ++j) u[j] = hp[(size_t)sid[j] * 64 + lane];
            float c[16];
            #pragma unroll
            for (int j = 0; j < 16; ++j) c[j] = dis[sid[j]] * dd;
            #pragma unroll
            for (int j = 0; j < 16; ++j) {
                a0 = fmaf(c[j], bflo(u[j]), a0);
                a1 = fmaf(c[j], bfhi(u[j]), a1);
            }
        }
        for (; i + 4 <= e; i += 4) {
            int sid[4];
            #pragma unroll
            for (int j = 0; j < 4; ++j) sid[j] = csr_src[i + j];
            uint32_t u[4];
            #pragma unroll
            for (int j = 0; j < 4; ++j) u[j] = hp[(size_t)sid[j] * 64 + lane];
            #pragma unroll
            for (int j = 0; j < 4; ++j) {
                float c = dis[sid[j]] * dd;
                a0 = fmaf(c, bflo(u[j]), a0);
                a1 = fmaf(c, bfhi(u[j]), a1);
            }
        }
        for (; i < e; ++i) {
            int s0 = csr_src[i];
            float c0 = dis[s0] * dd;
            uint32_t u0 = hp[(size_t)s0 * 64 + lane];
            a0 = fmaf(c0, bflo(u0), a0);
            a1 = fmaf(c0, bfhi(u0), a1);
        }
        float c2 = dd * dd;
        uint32_t u = hp[(size_t)wid * 64 + lane];
        a0 = fmaf(c2, bflo(u), a0) + bias[2 * lane];
        a1 = fmaf(c2, bfhi(u), a1) + bias[2 * lane + 1];
        *(float2*)(y + (size_t)wid * 128 + 2 * lane) = make_float2(a0, a1);
    } else {
        float a0 = 0.f;
        int i = s;
        for (; i + 16 <= e; i += 16) {
            int sid[16];
            #pragma unroll
            for (int j = 0; j < 16; ++j) sid[j] = csr_src[i + j];
            uint32_t u[16];
            #pragma unroll
            for (int j = 0; j < 16; ++j) u[j] = (uint32_t)h[(size_t)sid[j] * 64 + lane];
            float c[16];
            #pragma unroll
            for (int j = 0; j < 16; ++j) c[j] = dis[sid[j]] * dd;
            #pragma unroll
            for (int j = 0; j < 16; ++j) a0 = fmaf(c[j], bflo(u[j]), a0);
        }
        for (; i + 4 <= e; i += 4) {
            int sid[4];
            #pragma unroll
            for (int j = 0; j < 4; ++j) sid[j] = csr_src[i + j];
            uint32_t u[4];
            #pragma unroll
            for (int j = 0; j < 4; ++j) u[j] = (uint32_t)h[(size_t)sid[j] * 64 + lane];
            #pragma unroll
            for (int j = 0; j < 4; ++j) {
                float c = dis[sid[j]] * dd;
                a0 = fmaf(c, bflo(u[j]), a0);
            }
        }
        for (; i < e; ++i) {
            int s0 = csr_src[i];
            float c0 = dis[s0] * dd;
            a0 = fmaf(c0, bflo((uint32_t)h[(size_t)s0 * 64 + lane]), a0);
        }
        float c2 = dd * dd;
        a0 = fmaf(c2, bflo((uint32_t)h[(size_t)wid * 64 + lane]), a0) + bias[lane];
        y[(size_t)wid * 64 + lane] = a0;
    }
}

// ------------------------------------------------------------ BN statistics
template <int F>
__global__ __launch_bounds__(256) void colsum_kernel(
    const float* __restrict__ y, int n,
    float* __restrict__ sums, float* __restrict__ sumsq) {
    constexpr int CG = F / 4;
    constexpr int RP = 256 / CG;
    int t = threadIdx.x;
    int cg = t % CG, rt = t / CG;
    float4 s = make_float4(0.f, 0.f, 0.f, 0.f);
    float4 q = make_float4(0.f, 0.f, 0.f, 0.f);
    for (int row = blockIdx.x * RP + rt; row < n; row += gridDim.x * RP) {
        float4 v = *(const float4*)(y + (size_t)row * F + cg * 4);
        s.x += v.x; s.y += v.y; s.z += v.z; s.w += v.w;
        q.x += v.x * v.x; q.y += v.y * v.y; q.z += v.z * v.z; q.w += v.w * v.w;
    }
    __shared__ float4 rs[RP][CG], rq[RP][CG];
    rs[rt][cg] = s; rq[rt][cg] = q;
    __syncthreads();
    if (rt == 0) {
        #pragma unroll 4
        for (int j = 1; j < RP; ++j) {
            float4 o = rs[j][cg], p = rq[j][cg];
            s.x += o.x; s.y += o.y; s.z += o.z; s.w += o.w;
            q.x += p.x; q.y += p.y; q.z += p.z; q.w += p.w;
        }
        atomicAdd(&sums[cg * 4 + 0], s.x); atomicAdd(&sums[cg * 4 + 1], s.y);
        atomicAdd(&sums[cg * 4 + 2], s.z); atomicAdd(&sums[cg * 4 + 3], s.w);
        atomicAdd(&sumsq[cg * 4 + 0], q.x); atomicAdd(&sumsq[cg * 4 + 1], q.y);
        atomicAdd(&sumsq[cg * 4 + 2], q.z); atomicAdd(&sumsq[cg * 4 + 3], q.w);
    }
}

template <int F>
__global__ void finalize_kernel(const float* __restrict__ sums,
                                const float* __restrict__ sumsq,
                                const float* __restrict__ g, const float* __restrict__ be,
                                float* __restrict__ sc, float* __restrict__ sh, float n) {
    int c = threadIdx.x;
    if (c < F) {
        float m = sums[c] / n;
        float v = sumsq[c] / n - m * m;           // biased variance
        float r = rsqrtf(v + 1e-5f);
        float scale = r * g[c];
        sc[c] = scale;
        sh[c] = be[c] - m * scale;
    }
}

// ----------------------------------------------------------- final BN+ELU
__global__ __launch_bounds__(256) void out_kernel(
    const float* __restrict__ y, const float* __restrict__ sc,
    const float* __restrict__ sh, float* __restrict__ out, int total4) {
    int idx = blockIdx.x * 256 + threadIdx.x;
    if (idx >= total4) return;
    int cg = (idx & 15) * 4;
    float4 v = *(const float4*)(y + (size_t)idx * 4);
    float4 s4 = *(const float4*)(sc + cg);
    float4 h4 = *(const float4*)(sh + cg);
    v.x = eluf(v.x * s4.x + h4.x);
    v.y = eluf(v.y * s4.y + h4.y);
    v.z = eluf(v.z * s4.z + h4.z);
    v.w = eluf(v.w * s4.w + h4.w);
    *(float4*)(out + (size_t)idx * 4) = v;
}

// ---------------------------------------------------------------------------
extern "C" void kernel_launch(void* const* d_in, const int* in_sizes, int n_in,
                              void* d_out, int out_size, void* d_ws, size_t ws_size,
                              hipStream_t stream) {
    const float* x   = (const float*)d_in[0];
    const int*   edge = (const int*)d_in[1];
    const float* W0 = (const float*)d_in[2];
    const float* b0 = (const float*)d_in[3];
    const float* g0 = (const float*)d_in[4];
    const float* be0 = (const float*)d_in[5];
    const float* W1 = (const float*)d_in[6];
    const float* b1 = (const float*)d_in[7];
    const float* g1 = (const float*)d_in[8];
    const float* be1 = (const float*)d_in[9];
    const float* W2 = (const float*)d_in[10];
    const float* b2 = (const float*)d_in[11];
    const float* g2 = (const float*)d_in[12];
    const float* be2 = (const float*)d_in[13];

    const int n = in_sizes[0] / 128;     // 50000
    const int E = in_sizes[1] / 2;       // 1600000
    const int* esrc = edge;
    const int* edst = edge + E;

    const int NBUK = (n + 255) >> 8;               // 256-node buckets (<=256)
    const int EPC  = (E + NCH - 1) / NCH;          // edges per chunk

    char* w = (char*)d_ws;
    auto carve = [&](size_t bytes) -> void* {
        void* p = (void*)w;
        w += (bytes + 255) & ~(size_t)255;
        return p;
    };
    float*    y         = (float*)carve((size_t)n * 128 * 4);
    uint16_t* h         = (uint16_t*)carve((size_t)n * 128 * 2);
    int*      csr_src   = (int*)carve((size_t)E * 4);
    uint32_t* rec       = (uint32_t*)carve((size_t)E * 4);
    uint32_t* coarse    = (uint32_t*)carve((size_t)NBUK * NCH * 4);
    int*      beb       = (int*)carve((size_t)(NBUK + 1) * 4);
    int*      row_start = (int*)carve((size_t)(n + 1) * 4);
    float*    dis       = (float*)carve((size_t)n * 4);
    float*    sums      = (float*)carve(128 * 4);
    float*    sumsq     = (float*)carve(128 * 4);
    float*    sc        = (float*)carve(128 * 4);
    float*    sh        = (float*)carve(128 * 4);

    // ---- CSR build: two-level counting sort
    hist_coarse_kernel<<<NCH, 1024, 0, stream>>>(edst, coarse, E, EPC, NBUK);
    basescan_kernel<<<1, 1024, 0, stream>>>(coarse, beb, row_start, NBUK, E, n);
    partition_kernel<<<NCH, 1024, 0, stream>>>(esrc, edst, coarse, beb, rec, E, EPC, NBUK);
    fine_kernel<<<NBUK, 1024, 0, stream>>>(rec, beb, row_start, dis, csr_src, n);

    int gGemm = (n + 127) / 128;
    int gAgg  = (n + 3) / 4;

    // ---- layer 0 (in = x, no BN on input)
    gemm_kernel<128, false><<<gGemm, 512, 0, stream>>>(x, W0, nullptr, nullptr, h, n);
    agg_kernel<128><<<gAgg, 256, 0, stream>>>(h, row_start, csr_src, dis, b0, y, n);
    hipMemsetAsync(sums, 0, 128 * 4, stream);
    hipMemsetAsync(sumsq, 0, 128 * 4, stream);
    colsum_kernel<128><<<256, 256, 0, stream>>>(y, n, sums, sumsq);
    finalize_kernel<128><<<1, 128, 0, stream>>>(sums, sumsq, g0, be0, sc, sh, (float)n);

    // ---- layer 1
    gemm_kernel<128, true><<<gGemm, 512, 0, stream>>>(y, W1, sc, sh, h, n);
    agg_kernel<128><<<gAgg, 256, 0, stream>>>(h, row_start, csr_src, dis, b1, y, n);
    hipMemsetAsync(sums, 0, 128 * 4, stream);
    hipMemsetAsync(sumsq, 0, 128 * 4, stream);
    colsum_kernel<128><<<256, 256, 0, stream>>>(y, n, sums, sumsq);
    finalize_kernel<128><<<1, 128, 0, stream>>>(sums, sumsq, g1, be1, sc, sh, (float)n);

    // ---- layer 2 (F=64)
    gemm_kernel<64, true><<<gGemm, 512, 0, stream>>>(y, W2, sc, sh, h, n);
    agg_kernel<64><<<gAgg, 256, 0, stream>>>(h, row_start, csr_src, dis, b2, y, n);
    hipMemsetAsync(sums, 0, 64 * 4, stream);
    hipMemsetAsync(sumsq, 0, 64 * 4, stream);
    colsum_kernel<64><<<256, 256, 0, stream>>>(y, n, sums, sumsq);
    finalize_kernel<64><<<1, 64, 0, stream>>>(sums, sumsq, g2, be2, sc, sh, (float)n);

    // ---- final BN2 + ELU -> out
    int total4 = n * 16;
    out_kernel<<<(total4 + 255) / 256, 256, 0, stream>>>(y, sc, sh, (float*)d_out, total4);
}